// Round 11
// baseline (199.085 us; speedup 1.0000x reference)
//
#include <hip/hip_runtime.h>

// YOLO loss: preds (B,7,7,30) f32, labels (B,7,7,30) f32 -> scalar f32 (sum/B).
// R12: raise per-CU stream concurrency 2 -> 5 blocks/CU. Post-nt accounting:
// partial ~58us = ~3.3 TB/s reads vs 6.8 TB/s fills on the same machine; all
// pipes idle; R11 proved intra-block overlap is worthless (compute ~0.5us vs
// load ~2.5us per group). Hypothesis: 2 resident blocks/CU (61.4KB LDS each)
// give only ~1.7 effective request streams/CU. R12: BLOCK=128, each block
// does its 256-cell group as two sequential 128-cell halves through ONE
// 30.7KB LDS buffer -> 5 blocks/CU, 2.5x streams, stagger is inter-block.
// Exact tree preserved: w0,w1 (half A waves) and w2,w3 (half B waves) combine
// as ((w0+w1)+w2)+w3 == R4's wsum order; lb0 value identical via LDS or
// cached global path -> absmax 0.0. Partials/workspace/reduce unchanged.

#define BATCH 16384
#define S 7
#define C 30
#define NCELLS (BATCH * S * S)    // 802816
#define BLOCK 128                 // 2 waves
#define NC 256                    // cells per partial group
#define HALF 128                  // cells per staged half
#define NGRP (NCELLS / NC)        // 3136 partials (workspace unchanged)
#define F4_PER_HALF (HALF * C / 4)  // 960 float4 per array per half

typedef float f4v __attribute__((ext_vector_type(4)));

__device__ __forceinline__ f4v ntld(const f4v* p) {
    return __builtin_nontemporal_load(p);
}

__device__ __forceinline__ float sq(float v) { return v * v; }

__device__ __forceinline__ float iou_box(float acx, float acy, float aw, float ah,
                                         float bcx, float bcy, float bw, float bh) {
    float ax0 = acx - aw * 0.5f, ax1 = acx + aw * 0.5f;
    float ay0 = acy - ah * 0.5f, ay1 = acy + ah * 0.5f;
    float bx0 = bcx - bw * 0.5f, bx1 = bcx + bw * 0.5f;
    float by0 = bcy - bh * 0.5f, by1 = bcy + bh * 0.5f;
    float iw = fmaxf(fminf(ax1, bx1) - fmaxf(ax0, bx0), 0.0f);
    float ih = fmaxf(fminf(ay1, by1) - fmaxf(ay0, by0), 0.0f);
    float inter = iw * ih;
    float denom = aw * ah + bw * bh - inter + 1e-10f;
    return inter / denom;
}

// issue the 15 nt float4 loads for one 128-cell half (7 full rounds + tail)
__device__ __forceinline__ void stage_regs(const float* __restrict__ preds,
                                           const float* __restrict__ labels,
                                           int hbase, int tid,
                                           f4v* rp, f4v* rl) {
    const f4v* gp = reinterpret_cast<const f4v*>(preds  + (size_t)hbase * C);
    const f4v* gl = reinterpret_cast<const f4v*>(labels + (size_t)hbase * C);
    #pragma unroll
    for (int k = 0; k < 7; ++k) rl[k] = ntld(gl + tid + k * BLOCK);   // 0..895
    #pragma unroll
    for (int k = 0; k < 7; ++k) rp[k] = ntld(gp + tid + k * BLOCK);
    // tail f4 [896,960): wave0 -> labels, wave1 -> preds (wave-uniform branch)
    if (tid < 64) rl[7] = ntld(gl + 896 + tid);
    else          rp[7] = ntld(gp + 896 + (tid - 64));
}

__device__ __forceinline__ void write_lds(float* sp, float* sl, int tid,
                                          const f4v* rp, const f4v* rl) {
    f4v* s4l = reinterpret_cast<f4v*>(sl);
    f4v* s4p = reinterpret_cast<f4v*>(sp);
    #pragma unroll
    for (int k = 0; k < 7; ++k) s4l[tid + k * BLOCK] = rl[k];
    #pragma unroll
    for (int k = 0; k < 7; ++k) s4p[tid + k * BLOCK] = rp[k];
    if (tid < 64) s4l[896 + tid] = rl[7];
    else          s4p[896 + (tid - 64)] = rp[7];
}

// per-cell loss from LDS; hbase = half base cell (128 cells staged)
__device__ __forceinline__ float cell_loss(const float* __restrict__ sp,
                                           const float* __restrict__ sl,
                                           const float* __restrict__ labels,
                                           int hbase, int tid) {
    const float* p = sp + tid * C;
    const float* l = sl + tid * C;
    float pv[C], lv[C];
    #pragma unroll
    for (int i = 0; i < C / 2; ++i) {
        float2 tp = *reinterpret_cast<const float2*>(p + 2 * i);
        pv[2 * i] = tp.x; pv[2 * i + 1] = tp.y;
        float2 tl2 = *reinterpret_cast<const float2*>(l + 2 * i);
        lv[2 * i] = tl2.x; lv[2 * i + 1] = tl2.y;
    }

    // transposed label x-coord quirk: labels[b, x, y, 0]
    int cell = hbase + tid;
    int b    = cell / (S * S);
    int rem  = cell - b * (S * S);
    int y    = rem / S;
    int x    = rem - y * S;
    int pc   = b * (S * S) + x * S + y;
    float lb0;
    if (pc >= hbase && pc < hbase + HALF) {
        lb0 = sl[(pc - hbase) * C];           // partner staged in this half
    } else {
        lb0 = labels[(size_t)pc * C];          // cached (non-nt) scalar load
    }

    float iou1 = iou_box(pv[0], pv[1], pv[2], pv[3], lb0, lv[1], lv[2], lv[3]);
    float iou2 = iou_box(pv[5], pv[6], pv[7], pv[8], lb0, lv[1], lv[2], lv[3]);

    float b1 = 5.0f * (sq(pv[0] - lv[0]) + sq(pv[1] - lv[1]))
             + sq(sqrtf(pv[2]) - sqrtf(lv[2])) + sq(sqrtf(pv[3]) - sqrtf(lv[3]))
             + sq(iou1 - pv[4])
             + 0.5f * pv[9] * pv[9];

    float b2 = 5.0f * (sq(pv[5] - lv[5]) + sq(pv[6] - lv[6]))
             + sq(sqrtf(pv[7]) - sqrtf(lv[7])) + sq(sqrtf(pv[8]) - sqrtf(lv[8]))
             + sq(iou2 - pv[9])
             + 0.5f * pv[4] * pv[4];

    float cls = 0.0f;
    #pragma unroll
    for (int c = 10; c < C; ++c) cls += sq(lv[c] - pv[c]);

    float obj_loss   = ((iou1 > iou2) ? b1 : b2) + cls;
    float noobj_loss = 0.5f * (pv[4] * pv[4] + pv[9] * pv[9]);
    return (lv[4] == 1.0f) ? obj_loss : noobj_loss;
}

__global__ __launch_bounds__(BLOCK) void yolo_partial_kernel(
        const float* __restrict__ preds,
        const float* __restrict__ labels,
        float* __restrict__ partials) {
    __shared__ __align__(16) float sp[HALF * C];   // 15360 B
    __shared__ __align__(16) float sl[HALF * C];   // 15360 B
    __shared__ float wsA[2], wsB[2];

    const int tid  = threadIdx.x;
    const int lane = tid & 63;
    const int wv   = tid >> 6;                 // 2 waves
    const int g    = blockIdx.x;               // partial group
    const int hA   = g * NC;                   // half A base cell
    const int hB   = hA + HALF;                // half B base cell

    f4v rl[8], rp[8];

    // ---- half A: stage -> LDS -> compute ----
    stage_regs(preds, labels, hA, tid, rp, rl);
    write_lds(sp, sl, tid, rp, rl);
    __syncthreads();

    float loss = cell_loss(sp, sl, labels, hA, tid);
    #pragma unroll
    for (int off = 32; off > 0; off >>= 1)
        loss += __shfl_down(loss, off, 64);
    if (lane == 0) wsA[wv] = loss;             // w0, w1
    __syncthreads();                           // A's LDS reads retired

    // ---- half B: stage -> LDS -> compute ----
    stage_regs(preds, labels, hB, tid, rp, rl);
    write_lds(sp, sl, tid, rp, rl);
    __syncthreads();

    loss = cell_loss(sp, sl, labels, hB, tid);
    #pragma unroll
    for (int off = 32; off > 0; off >>= 1)
        loss += __shfl_down(loss, off, 64);
    if (lane == 0) wsB[wv] = loss;             // w2, w3
    __syncthreads();

    if (tid == 0) {
        // identical order to R4: ((w0+w1)+w2)+w3
        partials[g] = ((wsA[0] + wsA[1]) + wsB[0]) + wsB[1];
    }
}

__global__ __launch_bounds__(256) void yolo_reduce_kernel(
        const float* __restrict__ partials,
        float* __restrict__ out) {
    const int tid = threadIdx.x;
    float s = 0.0f;
    for (int i = tid; i < NGRP; i += 256) s += partials[i];

    #pragma unroll
    for (int off = 32; off > 0; off >>= 1)
        s += __shfl_down(s, off, 64);

    __shared__ float wsum[4];
    int lane = tid & 63;
    int wv   = tid >> 6;
    if (lane == 0) wsum[wv] = s;
    __syncthreads();
    if (tid == 0) {
        out[0] = (wsum[0] + wsum[1] + wsum[2] + wsum[3]) * (1.0f / (float)BATCH);
    }
}

extern "C" void kernel_launch(void* const* d_in, const int* in_sizes, int n_in,
                              void* d_out, int out_size, void* d_ws, size_t ws_size,
                              hipStream_t stream) {
    const float* preds  = (const float*)d_in[0];
    const float* labels = (const float*)d_in[1];
    float* out = (float*)d_out;
    float* partials = (float*)d_ws;   // NGRP floats = 12.25 KB (unchanged)

    yolo_partial_kernel<<<NGRP, BLOCK, 0, stream>>>(preds, labels, partials);
    yolo_reduce_kernel<<<1, 256, 0, stream>>>(partials, out);
}